// Round 5
// baseline (6027.981 us; speedup 1.0000x reference)
//
#include <hip/hip_runtime.h>
#include <hip/hip_bf16.h>

// ============================================================================
// SimpleGatedUnit: xx/x_in/x_out = (Xt @ W*) + b*  (bf16 MFMA GEMM, 51.5 GF)
// then 511-step scan:
//   z     = hsig(xx[s+1] + h@U + xx[s])
//   z_in  = hsig(x_in[s+1] + h@U_in + x_in[s] + bu_in)
//   z_out = softplus(x_out[s+1] + (z_in*h)@U_out + x_out[s] + bu_out)
//   h     = (1-z)*h + z*z_out
//
// Scan: 32 persistent blocks; block c owns 16 output cols, U slices in LDS.
// Cross-block h/g via relaxed agent-scope atomics (sc0 sc1: bypass to IC
// coherence point). R5 change: barrier arrival was 32 atomic fetch_adds on
// ONE cacheline (serialized RMW at the coherence point ~3us/round — the only
// component untouched by R3/R4's null results). Now: per-block FLAG STORES
// (32 independent words, no RMW, parallel arrival) + single gather-load
// polling (wave 0, lane i polls flags[i&31], __all(f>=phase)).
// ============================================================================

typedef __attribute__((ext_vector_type(4))) float  f32x4;
typedef __attribute__((ext_vector_type(4))) float  floatx4;
typedef __attribute__((ext_vector_type(8))) short  short8;
typedef __attribute__((ext_vector_type(4))) short  short4v;
typedef unsigned long long u64;

#define NSTEP  511
#define NBLK   32        // scan blocks (16 cols each)

// ws layout (bytes)
#define OFF_FLG  0                        // int flags[32] (128 B)
#define OFF_HBF  4096                     // h bf16 [64][512]            (64 KB)
#define OFF_GBF  (OFF_HBF + 65536)        // g bf16 [64][512]            (64 KB)
#define OFF_HF32 (OFF_GBF + 65536)        // h fp32 [64][512]           (128 KB)
#define OFF_UPK  (OFF_HF32 + 131072)      // packed U,U_in,U_out bf16  (1.5 MB)
#define OFF_WT   (OFF_UPK + 1572864)      // W^T bf16 [3][512 n][512 k](1.5 MB)
#define OFF_XX   (OFF_WT + 1572864)       // xx,x_in,x_out bf16 segment buffer
#define PER_T_BYTES (3u * 64u * 512u * 2u)  // bytes of xx per time row (196608)

__device__ __forceinline__ float b2f(short s) {
  unsigned u = ((unsigned)(unsigned short)s) << 16;
  return __builtin_bit_cast(float, u);
}
__device__ __forceinline__ short f2b(float f) {  // RNE fp32->bf16
  unsigned u = __builtin_bit_cast(unsigned, f);
  u += 0x7fffu + ((u >> 16) & 1u);
  return (short)(u >> 16);
}
__device__ __forceinline__ float hsig(float x) {
  return fminf(fmaxf(0.2f * x + 0.5f, 0.0f), 1.0f);
}
__device__ __forceinline__ float softplus_f(float x) {
  return fmaxf(x, 0.0f) + log1pf(expf(-fabsf(x)));
}

union Pk16 { u64 q[2]; short8 v; };

// 16B load from the agent coherence point (2x relaxed agent-scope b64 loads)
__device__ __forceinline__ short8 ld16_cp(const short* p) {
  const u64* q = (const u64*)p;
  Pk16 u;
  u.q[0] = __hip_atomic_load(q,     __ATOMIC_RELAXED, __HIP_MEMORY_SCOPE_AGENT);
  u.q[1] = __hip_atomic_load(q + 1, __ATOMIC_RELAXED, __HIP_MEMORY_SCOPE_AGENT);
  return u.v;
}
// 2B store to the agent coherence point
__device__ __forceinline__ void st2_cp(short* p, short v) {
  __hip_atomic_store(p, v, __ATOMIC_RELAXED, __HIP_MEMORY_SCOPE_AGENT);
}

// arrive: all block stores acked at IC, then set this block's flag = phase
__device__ __forceinline__ void bar_arrive(int* flags, int c, int phase) {
  asm volatile("s_waitcnt vmcnt(0)" ::: "memory");   // sc1 stores acked at IC
  __syncthreads();                                   // whole block done
  if (threadIdx.x == 0)
    __hip_atomic_store(&flags[c], phase, __ATOMIC_RELAXED, __HIP_MEMORY_SCOPE_AGENT);
}
// wait: wave 0 gathers all 32 flags (1 load), done when min >= phase
__device__ __forceinline__ void bar_wait(int* flags, int phase) {
  if (threadIdx.x < 64) {
    int* fp = &flags[threadIdx.x & 31];
    int guard = 0;
    for (;;) {
      int f = __hip_atomic_load(fp, __ATOMIC_RELAXED, __HIP_MEMORY_SCOPE_AGENT);
      if (__all(f >= phase)) break;
      if (++guard > (1 << 15)) break;  // safety valve: degrade, never hang
    }
  }
  __syncthreads();
}

// ---------------------------------------------------------------------------
// prep: pack U mats into B-fragment order bf16; transpose W mats to [n][k] bf16
// Upk[mat][c][kb][lane][j] = U[kb*32 + (lane>>4)*8 + j][c*16 + (lane&15)]
// ---------------------------------------------------------------------------
__global__ __launch_bounds__(256) void prep_kernel(
    const float* __restrict__ U0, const float* __restrict__ U1, const float* __restrict__ U2,
    const float* __restrict__ W0, const float* __restrict__ W1, const float* __restrict__ W2,
    short* __restrict__ Upk, short* __restrict__ Wt)
{
  int e = blockIdx.x * 256 + threadIdx.x;
  if (e < 786432) {
    int mat = e >> 18;
    int rem = e & 262143;
    int c   = rem >> 13;
    int r2  = rem & 8191;
    int kb  = r2 >> 9;
    int r3  = r2 & 511;
    int l = r3 >> 3, j = r3 & 7;
    int k = kb * 32 + ((l >> 4) << 3) + j;
    int d = c * 16 + (l & 15);
    const float* U = (mat == 0) ? U0 : (mat == 1 ? U1 : U2);
    Upk[e] = f2b(U[k * 512 + d]);
  } else if (e < 1572864) {
    int e2 = e - 786432;
    int mat = e2 >> 18;
    int rem = e2 & 262143;
    int n = rem >> 9, k = rem & 511;
    const float* W = (mat == 0) ? W0 : (mat == 1 ? W1 : W2);
    Wt[e2] = f2b(W[k * 512 + n]);
  }
}

__global__ __launch_bounds__(256) void init_kernel(short* h_bf, float* h_f32) {
  int e = blockIdx.x * 256 + threadIdx.x;
  if (e < 32768) { h_bf[e] = 0; h_f32[e] = 0.0f; }
}

// ---------------------------------------------------------------------------
// GEMM (per segment): out[mat][m][n] = bf16( X-row(base+m) . W[mat][:,n] + b )
// global row g = t*64 + b maps to X[b][t][:]. 128x128 tile, BK=32, 4 waves.
// Also resets the 32 barrier flags (block (0,0,0), tid<32).
// ---------------------------------------------------------------------------
__global__ __launch_bounds__(256) void gemm_xw(
    const float* __restrict__ X, const short* __restrict__ Wt,
    const float* __restrict__ bias0, const float* __restrict__ bias1,
    const float* __restrict__ bias2, short* __restrict__ out,
    int base_row, int cnt_rows, int* flags)
{
  if (blockIdx.x == 0 && blockIdx.y == 0 && blockIdx.z == 0 && threadIdx.x < 32)
    flags[threadIdx.x] = 0;
  __shared__ __align__(16) short Al[128][48];  // +16 pad: break 8-way conflicts
  __shared__ __align__(16) short Bl[128][48];
  const int bm = blockIdx.x, bn = blockIdx.y, mat = blockIdx.z;
  const short* Wm = Wt + (size_t)mat * (512 * 512);
  const float* bias = (mat == 0) ? bias0 : (mat == 1 ? bias1 : bias2);
  short* om = out + (size_t)mat * ((size_t)cnt_rows * 512);
  const int tid = threadIdx.x, lane = tid & 63, wid = tid >> 6;
  const int wm = wid >> 1, wn = wid & 1;
  const int m0 = bm * 128, n0g = bn * 128;
  f32x4 acc[4][4];
  #pragma unroll
  for (int i = 0; i < 4; ++i)
    #pragma unroll
    for (int j = 0; j < 4; ++j) acc[i][j] = (f32x4){0.f, 0.f, 0.f, 0.f};

  for (int k0 = 0; k0 < 512; k0 += 32) {
    #pragma unroll
    for (int i = 0; i < 4; ++i) {
      int q = tid + 256 * i;          // 0..1023 float4-slots (128 rows x 8)
      int r = q >> 3, seg = q & 7;
      int ml = m0 + r;
      short4v h4 = {0, 0, 0, 0};
      if (ml < cnt_rows) {
        int gl = base_row + ml;
        int t = gl >> 6, bb = gl & 63;
        floatx4 v = *(const floatx4*)(X + ((size_t)bb * 512 + t) * 512 + k0 + seg * 4);
        h4 = (short4v){ f2b(v[0]), f2b(v[1]), f2b(v[2]), f2b(v[3]) };
      }
      *(short4v*)&Al[r][seg * 4] = h4;
    }
    #pragma unroll
    for (int i = 0; i < 2; ++i) {
      int q = tid + 256 * i;          // 0..511 short8-slots (128 rows x 4)
      int r = q >> 2, seg = q & 3;
      *(short8*)&Bl[r][seg * 8] = *(const short8*)(Wm + (size_t)(n0g + r) * 512 + k0 + seg * 8);
    }
    __syncthreads();
    const int ko = (lane >> 4) * 8;
    short8 af[4], bf4[4];
    #pragma unroll
    for (int mt = 0; mt < 4; ++mt)
      af[mt] = *(const short8*)&Al[wm * 64 + mt * 16 + (lane & 15)][ko];
    #pragma unroll
    for (int nt = 0; nt < 4; ++nt)
      bf4[nt] = *(const short8*)&Bl[wn * 64 + nt * 16 + (lane & 15)][ko];
    #pragma unroll
    for (int mt = 0; mt < 4; ++mt)
      #pragma unroll
      for (int nt = 0; nt < 4; ++nt)
        acc[mt][nt] = __builtin_amdgcn_mfma_f32_16x16x32_bf16(af[mt], bf4[nt], acc[mt][nt], 0, 0, 0);
    __syncthreads();
  }
  // epilogue: + bias, store bf16.  C/D layout: col=lane&15, row=(lane>>4)*4+rr
  const int rq = lane >> 4, cq = lane & 15;
  #pragma unroll
  for (int mt = 0; mt < 4; ++mt) {
    #pragma unroll
    for (int nt = 0; nt < 4; ++nt) {
      int n = n0g + wn * 64 + nt * 16 + cq;
      float bv = bias[n];
      #pragma unroll
      for (int rr = 0; rr < 4; ++rr) {
        int m = m0 + wm * 64 + mt * 16 + rq * 4 + rr;
        if (m < cnt_rows) om[(size_t)m * 512 + n] = f2b(acc[mt][nt][rr] + bv);
      }
    }
  }
}

// ---------------------------------------------------------------------------
// scan segment: 32 blocks x 256 threads (4 waves). Block c owns cols
// [c*16, c*16+16). Wave w owns batch rows [w*16, w*16+16). U slices in LDS.
// xx holds nt local time rows (global steps s0 .. s0+nsteps).
// ---------------------------------------------------------------------------
__global__ __launch_bounds__(256, 1) void scan_kernel(
    short* h_bf, short* g_bf, float* h_f32,
    const short* __restrict__ Upk,
    const short* __restrict__ xx,
    int* flags,
    const float* __restrict__ bu_in, const float* __restrict__ bu_out,
    float* __restrict__ out,
    int s0, int nsteps, int nt)
{
  __shared__ __align__(16) short Ub[3][16][64][8];   // 48 KB, B-frag-packed
  const int tid = threadIdx.x, lane = tid & 63, wid = tid >> 6;
  const int c = blockIdx.x;
  const int n0 = c * 16;
  {
    const size_t cs = (size_t)c * 8192;
    short8* dst = (short8*)Ub;
    for (int i = tid; i < 3072; i += 256) {          // 48 KB in 12 iters
      int mat = i >> 10;
      int rem = i & 1023;
      dst[i] = *(const short8*)(Upk + (size_t)mat * 262144 + cs + (size_t)rem * 8);
    }
  }
  const int colg = n0 + (lane & 15);
  const float binr  = bu_in[colg];
  const float boutr = bu_out[colg];
  const int m0 = wid * 16;
  const int rowA = m0 + (lane & 15);    // A-frag row
  const int kofs = (lane >> 4) * 8;     // A-frag k-offset within K=32 block
  const size_t XSZ = (size_t)nt * 64 * 512;
  // own h tile fp32, C-frag layout: hown[r] = h[m0+(lane>>4)*4+r][colg]
  float hown[4];
  #pragma unroll
  for (int r = 0; r < 4; ++r)
    hown[r] = h_f32[(size_t)(m0 + (lane >> 4) * 4 + r) * 512 + colg];
  __syncthreads();

  for (int s = 0; s < nsteps; ++s) {
    // hoisted xx loads for stage 1 (read-only, cached) — overlap barrier wait
    float a1[4], a0[4], p1[4], p0[4];
    #pragma unroll
    for (int r = 0; r < 4; ++r) {
      int gr = m0 + (lane >> 4) * 4 + r;
      size_t i1 = ((size_t)(s + 1) * 64 + gr) * 512 + colg;
      size_t i0 = ((size_t)s * 64 + gr) * 512 + colg;
      a1[r] = b2f(xx[i1]);       a0[r] = b2f(xx[i0]);
      p1[r] = b2f(xx[XSZ + i1]); p0[r] = b2f(xx[XSZ + i0]);
    }
    if (s > 0) bar_wait(flags, 2 * s);            // prev step's h at IC

    // ---- stage 1: h@U, h@U_in. Issue ALL 16 A-frag loads, THEN mfma ----
    short8 afr[16];
    #pragma unroll
    for (int kb = 0; kb < 16; ++kb)
      afr[kb] = ld16_cp(h_bf + (size_t)rowA * 512 + kb * 32 + kofs);
    f32x4 accu  = {0.f, 0.f, 0.f, 0.f};
    f32x4 accin = {0.f, 0.f, 0.f, 0.f};
    #pragma unroll
    for (int kb = 0; kb < 16; ++kb) {
      short8 b0 = *((const short8*)Ub + ((0 * 16 + kb) * 64 + lane));
      short8 b1 = *((const short8*)Ub + ((1 * 16 + kb) * 64 + lane));
      accu  = __builtin_amdgcn_mfma_f32_16x16x32_bf16(afr[kb], b0, accu, 0, 0, 0);
      accin = __builtin_amdgcn_mfma_f32_16x16x32_bf16(afr[kb], b1, accin, 0, 0, 0);
    }
    float zr[4];
    #pragma unroll
    for (int r = 0; r < 4; ++r) {
      int gr = m0 + (lane >> 4) * 4 + r;
      zr[r] = hsig(a1[r] + accu[r] + a0[r]);
      float zin = hsig(p1[r] + accin[r] + p0[r] + binr);
      st2_cp(g_bf + (size_t)gr * 512 + colg, f2b(zin * hown[r]));
    }
    bar_arrive(flags, c, 2 * s + 1);               // g published

    // hoisted xx loads for stage 2 — overlap barrier wait
    float q1[4], q0[4];
    #pragma unroll
    for (int r = 0; r < 4; ++r) {
      int gr = m0 + (lane >> 4) * 4 + r;
      size_t i1 = ((size_t)(s + 1) * 64 + gr) * 512 + colg;
      size_t i0 = ((size_t)s * 64 + gr) * 512 + colg;
      q1[r] = b2f(xx[2 * XSZ + i1]); q0[r] = b2f(xx[2 * XSZ + i0]);
    }
    bar_wait(flags, 2 * s + 1);                    // everyone's g at IC

    // ---- stage 2: (z_in*h)@U_out. Same pipelined-load structure ----
    short8 gfr[16];
    #pragma unroll
    for (int kb = 0; kb < 16; ++kb)
      gfr[kb] = ld16_cp(g_bf + (size_t)rowA * 512 + kb * 32 + kofs);
    f32x4 acco = {0.f, 0.f, 0.f, 0.f};
    #pragma unroll
    for (int kb = 0; kb < 16; ++kb) {
      short8 b2 = *((const short8*)Ub + ((2 * 16 + kb) * 64 + lane));
      acco = __builtin_amdgcn_mfma_f32_16x16x32_bf16(gfr[kb], b2, acco, 0, 0, 0);
    }
    #pragma unroll
    for (int r = 0; r < 4; ++r) {
      int gr = m0 + (lane >> 4) * 4 + r;
      float pre = q1[r] + acco[r] + q0[r] + boutr;
      float zo = softplus_f(pre);
      float hn = (1.0f - zr[r]) * hown[r] + zr[r] * zo;
      hown[r] = hn;
      st2_cp(h_bf + (size_t)gr * 512 + colg, f2b(hn));
      if (s0 + s == NSTEP - 1) out[(size_t)gr * 512 + colg] = hn;
    }
    if (s < nsteps - 1) bar_arrive(flags, c, 2 * s + 2);  // h published
  }
  // persist fp32 h for the next segment (launch boundary = global sync)
  #pragma unroll
  for (int r = 0; r < 4; ++r)
    h_f32[(size_t)(m0 + (lane >> 4) * 4 + r) * 512 + colg] = hown[r];
}

extern "C" void kernel_launch(void* const* d_in, const int* in_sizes, int n_in,
                              void* d_out, int out_size, void* d_ws, size_t ws_size,
                              hipStream_t stream)
{
  const float* X      = (const float*)d_in[0];
  const float* W      = (const float*)d_in[1];
  const float* b      = (const float*)d_in[2];
  const float* W_in   = (const float*)d_in[3];
  const float* b_in   = (const float*)d_in[4];
  const float* W_out  = (const float*)d_in[5];
  const float* b_out  = (const float*)d_in[6];
  const float* U      = (const float*)d_in[7];
  const float* U_in   = (const float*)d_in[8];
  const float* U_out  = (const float*)d_in[9];
  const float* bu_in  = (const float*)d_in[10];
  const float* bu_out = (const float*)d_in[11];
  float* out = (float*)d_out;
  char* ws = (char*)d_ws;
  int*   flags = (int*)(ws + OFF_FLG);
  short* h_bf = (short*)(ws + OFF_HBF);
  short* g_bf = (short*)(ws + OFF_GBF);
  float* h_f32= (float*)(ws + OFF_HF32);
  short* Upk  = (short*)(ws + OFF_UPK);
  short* Wt   = (short*)(ws + OFF_WT);
  short* xx   = (short*)(ws + OFF_XX);

  // size the scan segment to the available workspace
  size_t avail = (ws_size > (size_t)OFF_XX) ? ws_size - (size_t)OFF_XX : 0;
  int max_t = (int)(avail / PER_T_BYTES);          // storable time rows
  if (max_t > 512) max_t = 512;
  int SEG = max_t - 1;                             // steps per segment
  if (SEG < 1) SEG = 1;                            // (ws too small: best effort)

  prep_kernel<<<6144, 256, 0, stream>>>(U, U_in, U_out, W, W_in, W_out, Upk, Wt);
  init_kernel<<<128, 256, 0, stream>>>(h_bf, h_f32);

  int s0 = 0;
  while (s0 < NSTEP) {
    int nsteps = NSTEP - s0; if (nsteps > SEG) nsteps = SEG;
    int nt = nsteps + 1;
    int rows = nt * 64;
    int gx = (rows + 127) / 128;
    gemm_xw<<<dim3(gx, 4, 3), 256, 0, stream>>>(X, Wt, b, b_in, b_out, xx,
                                                s0 * 64, rows, flags);
    scan_kernel<<<NBLK, 256, 0, stream>>>(h_bf, g_bf, h_f32, Upk, xx, flags,
                                          bu_in, bu_out, out, s0, nsteps, nt);
    s0 += nsteps;
  }
}

// Round 6
// 4717.467 us; speedup vs baseline: 1.2778x; 1.2778x over previous
//
#include <hip/hip_runtime.h>
#include <hip/hip_bf16.h>

// ============================================================================
// SimpleGatedUnit: xx/x_in/x_out = (Xt @ W*) + b*  (bf16 MFMA GEMM, 51.5 GF)
// then 511-step scan (see reference in header comments of earlier rounds).
//
// Scan: 32 persistent blocks; block c owns 16 output cols, U slices in LDS.
// Cross-block h/g via agent-scope (sc0 sc1 -> IC) loads/stores; flag-array
// barrier. R6 change: R4's "batched" IC loads were silently re-serialized by
// the compiler (VGPR=84 proved frags never co-resident; 16 dependent IC RTTs
// = ~11us/step = the whole cost). Now the 16 fragment loads + vmcnt(0) are
// ONE inline-asm block (early-clobber outputs, immediate offsets) the
// compiler cannot tear apart: stage cost 16*RTT -> 1*RTT.
// ============================================================================

typedef __attribute__((ext_vector_type(4))) float  f32x4;
typedef __attribute__((ext_vector_type(4))) float  floatx4;
typedef __attribute__((ext_vector_type(8))) short  short8;
typedef __attribute__((ext_vector_type(4))) short  short4v;
typedef unsigned long long u64;

#define NSTEP  511
#define NBLK   32        // scan blocks (16 cols each)

// ws layout (bytes)
#define OFF_FLG  0                        // int flags[32] (128 B)
#define OFF_HBF  4096                     // h bf16 [64][512]            (64 KB)
#define OFF_GBF  (OFF_HBF + 65536)        // g bf16 [64][512]            (64 KB)
#define OFF_HF32 (OFF_GBF + 65536)        // h fp32 [64][512]           (128 KB)
#define OFF_UPK  (OFF_HF32 + 131072)      // packed U,U_in,U_out bf16  (1.5 MB)
#define OFF_WT   (OFF_UPK + 1572864)      // W^T bf16 [3][512 n][512 k](1.5 MB)
#define OFF_XX   (OFF_WT + 1572864)       // xx,x_in,x_out bf16 segment buffer
#define PER_T_BYTES (3u * 64u * 512u * 2u)  // bytes of xx per time row (196608)

__device__ __forceinline__ float b2f(short s) {
  unsigned u = ((unsigned)(unsigned short)s) << 16;
  return __builtin_bit_cast(float, u);
}
__device__ __forceinline__ short f2b(float f) {  // RNE fp32->bf16
  unsigned u = __builtin_bit_cast(unsigned, f);
  u += 0x7fffu + ((u >> 16) & 1u);
  return (short)(u >> 16);
}
__device__ __forceinline__ float hsig(float x) {
  return fminf(fmaxf(0.2f * x + 0.5f, 0.0f), 1.0f);
}
__device__ __forceinline__ float softplus_f(float x) {
  return fmaxf(x, 0.0f) + log1pf(expf(-fabsf(x)));
}

// 2B store to the agent coherence point
__device__ __forceinline__ void st2_cp(short* p, short v) {
  __hip_atomic_store(p, v, __ATOMIC_RELAXED, __HIP_MEMORY_SCOPE_AGENT);
}

// 16 x 16B fragment loads from IC, issued back-to-back in ONE asm block the
// compiler cannot re-serialize. p = per-thread base (bytes stride 64 per kb).
__device__ __forceinline__ void ld_frags16(const short* p, short8 f[16]) {
  short8 f0,f1,f2,f3,f4,f5,f6,f7,f8,f9,f10,f11,f12,f13,f14,f15;
  asm volatile(
    "global_load_dwordx4 %0,  %16, off sc0 sc1\n\t"
    "global_load_dwordx4 %1,  %16, off offset:64 sc0 sc1\n\t"
    "global_load_dwordx4 %2,  %16, off offset:128 sc0 sc1\n\t"
    "global_load_dwordx4 %3,  %16, off offset:192 sc0 sc1\n\t"
    "global_load_dwordx4 %4,  %16, off offset:256 sc0 sc1\n\t"
    "global_load_dwordx4 %5,  %16, off offset:320 sc0 sc1\n\t"
    "global_load_dwordx4 %6,  %16, off offset:384 sc0 sc1\n\t"
    "global_load_dwordx4 %7,  %16, off offset:448 sc0 sc1\n\t"
    "global_load_dwordx4 %8,  %16, off offset:512 sc0 sc1\n\t"
    "global_load_dwordx4 %9,  %16, off offset:576 sc0 sc1\n\t"
    "global_load_dwordx4 %10, %16, off offset:640 sc0 sc1\n\t"
    "global_load_dwordx4 %11, %16, off offset:704 sc0 sc1\n\t"
    "global_load_dwordx4 %12, %16, off offset:768 sc0 sc1\n\t"
    "global_load_dwordx4 %13, %16, off offset:832 sc0 sc1\n\t"
    "global_load_dwordx4 %14, %16, off offset:896 sc0 sc1\n\t"
    "global_load_dwordx4 %15, %16, off offset:960 sc0 sc1\n\t"
    "s_waitcnt vmcnt(0)"
    : "=&v"(f0), "=&v"(f1), "=&v"(f2), "=&v"(f3),
      "=&v"(f4), "=&v"(f5), "=&v"(f6), "=&v"(f7),
      "=&v"(f8), "=&v"(f9), "=&v"(f10), "=&v"(f11),
      "=&v"(f12), "=&v"(f13), "=&v"(f14), "=&v"(f15)
    : "v"(p)
    : "memory");
  f[0]=f0; f[1]=f1; f[2]=f2; f[3]=f3; f[4]=f4; f[5]=f5; f[6]=f6; f[7]=f7;
  f[8]=f8; f[9]=f9; f[10]=f10; f[11]=f11; f[12]=f12; f[13]=f13; f[14]=f14; f[15]=f15;
}

// arrive: all block stores acked at IC, then set this block's flag = phase
__device__ __forceinline__ void bar_arrive(int* flags, int c, int phase) {
  asm volatile("s_waitcnt vmcnt(0)" ::: "memory");   // sc1 stores acked at IC
  __syncthreads();                                   // whole block done
  if (threadIdx.x == 0)
    __hip_atomic_store(&flags[c], phase, __ATOMIC_RELAXED, __HIP_MEMORY_SCOPE_AGENT);
}
// wait: wave 0 gathers all 32 flags (1 load), done when min >= phase
__device__ __forceinline__ void bar_wait(int* flags, int phase) {
  if (threadIdx.x < 64) {
    int* fp = &flags[threadIdx.x & 31];
    int guard = 0;
    for (;;) {
      int f = __hip_atomic_load(fp, __ATOMIC_RELAXED, __HIP_MEMORY_SCOPE_AGENT);
      if (__all(f >= phase)) break;
      if (++guard > (1 << 15)) break;  // safety valve: degrade, never hang
    }
  }
  __syncthreads();
}

// ---------------------------------------------------------------------------
// prep: pack U mats into B-fragment order bf16; transpose W mats to [n][k] bf16
// Upk[mat][c][kb][lane][j] = U[kb*32 + (lane>>4)*8 + j][c*16 + (lane&15)]
// ---------------------------------------------------------------------------
__global__ __launch_bounds__(256) void prep_kernel(
    const float* __restrict__ U0, const float* __restrict__ U1, const float* __restrict__ U2,
    const float* __restrict__ W0, const float* __restrict__ W1, const float* __restrict__ W2,
    short* __restrict__ Upk, short* __restrict__ Wt)
{
  int e = blockIdx.x * 256 + threadIdx.x;
  if (e < 786432) {
    int mat = e >> 18;
    int rem = e & 262143;
    int c   = rem >> 13;
    int r2  = rem & 8191;
    int kb  = r2 >> 9;
    int r3  = r2 & 511;
    int l = r3 >> 3, j = r3 & 7;
    int k = kb * 32 + ((l >> 4) << 3) + j;
    int d = c * 16 + (l & 15);
    const float* U = (mat == 0) ? U0 : (mat == 1 ? U1 : U2);
    Upk[e] = f2b(U[k * 512 + d]);
  } else if (e < 1572864) {
    int e2 = e - 786432;
    int mat = e2 >> 18;
    int rem = e2 & 262143;
    int n = rem >> 9, k = rem & 511;
    const float* W = (mat == 0) ? W0 : (mat == 1 ? W1 : W2);
    Wt[e2] = f2b(W[k * 512 + n]);
  }
}

__global__ __launch_bounds__(256) void init_kernel(short* h_bf, float* h_f32) {
  int e = blockIdx.x * 256 + threadIdx.x;
  if (e < 32768) { h_bf[e] = 0; h_f32[e] = 0.0f; }
}

// ---------------------------------------------------------------------------
// GEMM (per segment): out[mat][m][n] = bf16( X-row(base+m) . W[mat][:,n] + b )
// global row g = t*64 + b maps to X[b][t][:]. 128x128 tile, BK=32, 4 waves.
// Also resets the 32 barrier flags (block (0,0,0), tid<32).
// ---------------------------------------------------------------------------
__global__ __launch_bounds__(256) void gemm_xw(
    const float* __restrict__ X, const short* __restrict__ Wt,
    const float* __restrict__ bias0, const float* __restrict__ bias1,
    const float* __restrict__ bias2, short* __restrict__ out,
    int base_row, int cnt_rows, int* flags)
{
  if (blockIdx.x == 0 && blockIdx.y == 0 && blockIdx.z == 0 && threadIdx.x < 32)
    flags[threadIdx.x] = 0;
  __shared__ __align__(16) short Al[128][48];  // +16 pad: break 8-way conflicts
  __shared__ __align__(16) short Bl[128][48];
  const int bm = blockIdx.x, bn = blockIdx.y, mat = blockIdx.z;
  const short* Wm = Wt + (size_t)mat * (512 * 512);
  const float* bias = (mat == 0) ? bias0 : (mat == 1 ? bias1 : bias2);
  short* om = out + (size_t)mat * ((size_t)cnt_rows * 512);
  const int tid = threadIdx.x, lane = tid & 63, wid = tid >> 6;
  const int wm = wid >> 1, wn = wid & 1;
  const int m0 = bm * 128, n0g = bn * 128;
  f32x4 acc[4][4];
  #pragma unroll
  for (int i = 0; i < 4; ++i)
    #pragma unroll
    for (int j = 0; j < 4; ++j) acc[i][j] = (f32x4){0.f, 0.f, 0.f, 0.f};

  for (int k0 = 0; k0 < 512; k0 += 32) {
    #pragma unroll
    for (int i = 0; i < 4; ++i) {
      int q = tid + 256 * i;          // 0..1023 float4-slots (128 rows x 8)
      int r = q >> 3, seg = q & 7;
      int ml = m0 + r;
      short4v h4 = {0, 0, 0, 0};
      if (ml < cnt_rows) {
        int gl = base_row + ml;
        int t = gl >> 6, bb = gl & 63;
        floatx4 v = *(const floatx4*)(X + ((size_t)bb * 512 + t) * 512 + k0 + seg * 4);
        h4 = (short4v){ f2b(v[0]), f2b(v[1]), f2b(v[2]), f2b(v[3]) };
      }
      *(short4v*)&Al[r][seg * 4] = h4;
    }
    #pragma unroll
    for (int i = 0; i < 2; ++i) {
      int q = tid + 256 * i;          // 0..511 short8-slots (128 rows x 4)
      int r = q >> 2, seg = q & 3;
      *(short8*)&Bl[r][seg * 8] = *(const short8*)(Wm + (size_t)(n0g + r) * 512 + k0 + seg * 8);
    }
    __syncthreads();
    const int ko = (lane >> 4) * 8;
    short8 af[4], bf4[4];
    #pragma unroll
    for (int mt = 0; mt < 4; ++mt)
      af[mt] = *(const short8*)&Al[wm * 64 + mt * 16 + (lane & 15)][ko];
    #pragma unroll
    for (int nt = 0; nt < 4; ++nt)
      bf4[nt] = *(const short8*)&Bl[wn * 64 + nt * 16 + (lane & 15)][ko];
    #pragma unroll
    for (int mt = 0; mt < 4; ++mt)
      #pragma unroll
      for (int nt = 0; nt < 4; ++nt)
        acc[mt][nt] = __builtin_amdgcn_mfma_f32_16x16x32_bf16(af[mt], bf4[nt], acc[mt][nt], 0, 0, 0);
    __syncthreads();
  }
  // epilogue: + bias, store bf16.  C/D layout: col=lane&15, row=(lane>>4)*4+rr
  const int rq = lane >> 4, cq = lane & 15;
  #pragma unroll
  for (int mt = 0; mt < 4; ++mt) {
    #pragma unroll
    for (int nt = 0; nt < 4; ++nt) {
      int n = n0g + wn * 64 + nt * 16 + cq;
      float bv = bias[n];
      #pragma unroll
      for (int rr = 0; rr < 4; ++rr) {
        int m = m0 + wm * 64 + mt * 16 + rq * 4 + rr;
        if (m < cnt_rows) om[(size_t)m * 512 + n] = f2b(acc[mt][nt][rr] + bv);
      }
    }
  }
}

// ---------------------------------------------------------------------------
// scan segment: 32 blocks x 256 threads (4 waves). Block c owns cols
// [c*16, c*16+16). Wave w owns batch rows [w*16, w*16+16). U slices in LDS.
// xx holds nt local time rows (global steps s0 .. s0+nsteps).
// ---------------------------------------------------------------------------
__global__ __launch_bounds__(256, 1) void scan_kernel(
    short* h_bf, short* g_bf, float* h_f32,
    const short* __restrict__ Upk,
    const short* __restrict__ xx,
    int* flags,
    const float* __restrict__ bu_in, const float* __restrict__ bu_out,
    float* __restrict__ out,
    int s0, int nsteps, int nt)
{
  __shared__ __align__(16) short Ub[3][16][64][8];   // 48 KB, B-frag-packed
  const int tid = threadIdx.x, lane = tid & 63, wid = tid >> 6;
  const int c = blockIdx.x;
  const int n0 = c * 16;
  {
    const size_t cs = (size_t)c * 8192;
    short8* dst = (short8*)Ub;
    for (int i = tid; i < 3072; i += 256) {          // 48 KB in 12 iters
      int mat = i >> 10;
      int rem = i & 1023;
      dst[i] = *(const short8*)(Upk + (size_t)mat * 262144 + cs + (size_t)rem * 8);
    }
  }
  const int colg = n0 + (lane & 15);
  const float binr  = bu_in[colg];
  const float boutr = bu_out[colg];
  const int m0 = wid * 16;
  const int rowA = m0 + (lane & 15);    // A-frag row
  const int kofs = (lane >> 4) * 8;     // A-frag k-offset within K=32 block
  const size_t XSZ = (size_t)nt * 64 * 512;
  const short* hbase = h_bf + (size_t)rowA * 512 + kofs;  // frag base (kb stride 64B)
  const short* gbase = g_bf + (size_t)rowA * 512 + kofs;
  // own h tile fp32, C-frag layout: hown[r] = h[m0+(lane>>4)*4+r][colg]
  float hown[4];
  #pragma unroll
  for (int r = 0; r < 4; ++r)
    hown[r] = h_f32[(size_t)(m0 + (lane >> 4) * 4 + r) * 512 + colg];
  __syncthreads();

  for (int s = 0; s < nsteps; ++s) {
    // hoisted xx loads for stage 1 (read-only, cached) — overlap barrier wait
    float a1[4], a0[4], p1[4], p0[4];
    #pragma unroll
    for (int r = 0; r < 4; ++r) {
      int gr = m0 + (lane >> 4) * 4 + r;
      size_t i1 = ((size_t)(s + 1) * 64 + gr) * 512 + colg;
      size_t i0 = ((size_t)s * 64 + gr) * 512 + colg;
      a1[r] = b2f(xx[i1]);       a0[r] = b2f(xx[i0]);
      p1[r] = b2f(xx[XSZ + i1]); p0[r] = b2f(xx[XSZ + i0]);
    }
    if (s > 0) bar_wait(flags, 2 * s);            // prev step's h at IC

    // ---- stage 1: h@U, h@U_in. 16 frag loads in ONE asm block, then mfma ----
    short8 afr[16];
    ld_frags16(hbase, afr);
    f32x4 accu  = {0.f, 0.f, 0.f, 0.f};
    f32x4 accin = {0.f, 0.f, 0.f, 0.f};
    #pragma unroll
    for (int kb = 0; kb < 16; ++kb) {
      short8 b0 = *((const short8*)Ub + ((0 * 16 + kb) * 64 + lane));
      short8 b1 = *((const short8*)Ub + ((1 * 16 + kb) * 64 + lane));
      accu  = __builtin_amdgcn_mfma_f32_16x16x32_bf16(afr[kb], b0, accu, 0, 0, 0);
      accin = __builtin_amdgcn_mfma_f32_16x16x32_bf16(afr[kb], b1, accin, 0, 0, 0);
    }
    float zr[4];
    #pragma unroll
    for (int r = 0; r < 4; ++r) {
      int gr = m0 + (lane >> 4) * 4 + r;
      zr[r] = hsig(a1[r] + accu[r] + a0[r]);
      float zin = hsig(p1[r] + accin[r] + p0[r] + binr);
      st2_cp(g_bf + (size_t)gr * 512 + colg, f2b(zin * hown[r]));
    }
    bar_arrive(flags, c, 2 * s + 1);               // g published

    // hoisted xx loads for stage 2 — overlap barrier wait
    float q1[4], q0[4];
    #pragma unroll
    for (int r = 0; r < 4; ++r) {
      int gr = m0 + (lane >> 4) * 4 + r;
      size_t i1 = ((size_t)(s + 1) * 64 + gr) * 512 + colg;
      size_t i0 = ((size_t)s * 64 + gr) * 512 + colg;
      q1[r] = b2f(xx[2 * XSZ + i1]); q0[r] = b2f(xx[2 * XSZ + i0]);
    }
    bar_wait(flags, 2 * s + 1);                    // everyone's g at IC

    // ---- stage 2: (z_in*h)@U_out. Same one-asm-block load structure ----
    short8 gfr[16];
    ld_frags16(gbase, gfr);
    f32x4 acco = {0.f, 0.f, 0.f, 0.f};
    #pragma unroll
    for (int kb = 0; kb < 16; ++kb) {
      short8 b2 = *((const short8*)Ub + ((2 * 16 + kb) * 64 + lane));
      acco = __builtin_amdgcn_mfma_f32_16x16x32_bf16(gfr[kb], b2, acco, 0, 0, 0);
    }
    #pragma unroll
    for (int r = 0; r < 4; ++r) {
      int gr = m0 + (lane >> 4) * 4 + r;
      float pre = q1[r] + acco[r] + q0[r] + boutr;
      float zo = softplus_f(pre);
      float hn = (1.0f - zr[r]) * hown[r] + zr[r] * zo;
      hown[r] = hn;
      st2_cp(h_bf + (size_t)gr * 512 + colg, f2b(hn));
      if (s0 + s == NSTEP - 1) out[(size_t)gr * 512 + colg] = hn;
    }
    if (s < nsteps - 1) bar_arrive(flags, c, 2 * s + 2);  // h published
  }
  // persist fp32 h for the next segment (launch boundary = global sync)
  #pragma unroll
  for (int r = 0; r < 4; ++r)
    h_f32[(size_t)(m0 + (lane >> 4) * 4 + r) * 512 + colg] = hown[r];
}

extern "C" void kernel_launch(void* const* d_in, const int* in_sizes, int n_in,
                              void* d_out, int out_size, void* d_ws, size_t ws_size,
                              hipStream_t stream)
{
  const float* X      = (const float*)d_in[0];
  const float* W      = (const float*)d_in[1];
  const float* b      = (const float*)d_in[2];
  const float* W_in   = (const float*)d_in[3];
  const float* b_in   = (const float*)d_in[4];
  const float* W_out  = (const float*)d_in[5];
  const float* b_out  = (const float*)d_in[6];
  const float* U      = (const float*)d_in[7];
  const float* U_in   = (const float*)d_in[8];
  const float* U_out  = (const float*)d_in[9];
  const float* bu_in  = (const float*)d_in[10];
  const float* bu_out = (const float*)d_in[11];
  float* out = (float*)d_out;
  char* ws = (char*)d_ws;
  int*   flags = (int*)(ws + OFF_FLG);
  short* h_bf = (short*)(ws + OFF_HBF);
  short* g_bf = (short*)(ws + OFF_GBF);
  float* h_f32= (float*)(ws + OFF_HF32);
  short* Upk  = (short*)(ws + OFF_UPK);
  short* Wt   = (short*)(ws + OFF_WT);
  short* xx   = (short*)(ws + OFF_XX);

  // size the scan segment to the available workspace
  size_t avail = (ws_size > (size_t)OFF_XX) ? ws_size - (size_t)OFF_XX : 0;
  int max_t = (int)(avail / PER_T_BYTES);          // storable time rows
  if (max_t > 512) max_t = 512;
  int SEG = max_t - 1;                             // steps per segment
  if (SEG < 1) SEG = 1;                            // (ws too small: best effort)

  prep_kernel<<<6144, 256, 0, stream>>>(U, U_in, U_out, W, W_in, W_out, Upk, Wt);
  init_kernel<<<128, 256, 0, stream>>>(h_bf, h_f32);

  int s0 = 0;
  while (s0 < NSTEP) {
    int nsteps = NSTEP - s0; if (nsteps > SEG) nsteps = SEG;
    int nt = nsteps + 1;
    int rows = nt * 64;
    int gx = (rows + 127) / 128;
    gemm_xw<<<dim3(gx, 4, 3), 256, 0, stream>>>(X, Wt, b, b_in, b_out, xx,
                                                s0 * 64, rows, flags);
    scan_kernel<<<NBLK, 256, 0, stream>>>(h_bf, g_bf, h_f32, Upk, xx, flags,
                                          bu_in, bu_out, out, s0, nsteps, nt);
    s0 += nsteps;
  }
}

// Round 7
// 3559.794 us; speedup vs baseline: 1.6934x; 1.3252x over previous
//
#include <hip/hip_runtime.h>
#include <hip/hip_bf16.h>

// ============================================================================
// SimpleGatedUnit: xx/x_in/x_out = (Xt @ W*) + b*  (bf16 MFMA GEMM, 51.5 GF)
// then 511-step scan (z/z_in/z_out gated recurrence).
//
// Scan: 32 persistent blocks; block c owns 16 output cols, U slices in LDS.
// Cross-block h/g via agent-scope (sc0 sc1 -> IC) loads/stores; flag-array
// barrier. R7 change: h/g exchange buffers re-laid out from row-major
// [64][512] to FRAGMENT-MAJOR [w][kb][g][r15][j] so each of the 16 frag-load
// instructions reads ONE contiguous 1KB run (16 lines, streamable) instead of
// 64 scattered 1KB-strided 16B slivers (64 lines, 4x amplification). Stores
// coalesce to contiguous 512B runs. Theory: exchange is IC-transaction-bound.
// ============================================================================

typedef __attribute__((ext_vector_type(4))) float  f32x4;
typedef __attribute__((ext_vector_type(4))) float  floatx4;
typedef __attribute__((ext_vector_type(8))) short  short8;
typedef __attribute__((ext_vector_type(4))) short  short4v;
typedef unsigned long long u64;

#define NSTEP  511
#define NBLK   32        // scan blocks (16 cols each)

// ws layout (bytes)
#define OFF_FLG  0                        // int flags[32] (128 B)
#define OFF_HBF  4096                     // h bf16 frag-major [64*512]  (64 KB)
#define OFF_GBF  (OFF_HBF + 65536)        // g bf16 frag-major [64*512]  (64 KB)
#define OFF_HF32 (OFF_GBF + 65536)        // h fp32 [64][512] row-major (128 KB)
#define OFF_UPK  (OFF_HF32 + 131072)      // packed U,U_in,U_out bf16  (1.5 MB)
#define OFF_WT   (OFF_UPK + 1572864)      // W^T bf16 [3][512 n][512 k](1.5 MB)
#define OFF_XX   (OFF_WT + 1572864)       // xx,x_in,x_out bf16 segment buffer
#define PER_T_BYTES (3u * 64u * 512u * 2u)  // bytes of xx per time row (196608)

__device__ __forceinline__ float b2f(short s) {
  unsigned u = ((unsigned)(unsigned short)s) << 16;
  return __builtin_bit_cast(float, u);
}
__device__ __forceinline__ short f2b(float f) {  // RNE fp32->bf16
  unsigned u = __builtin_bit_cast(unsigned, f);
  u += 0x7fffu + ((u >> 16) & 1u);
  return (short)(u >> 16);
}
__device__ __forceinline__ float hsig(float x) {
  return fminf(fmaxf(0.2f * x + 0.5f, 0.0f), 1.0f);
}
__device__ __forceinline__ float softplus_f(float x) {
  return fmaxf(x, 0.0f) + log1pf(expf(-fabsf(x)));
}

// 2B store to the agent coherence point
__device__ __forceinline__ void st2_cp(short* p, short v) {
  __hip_atomic_store(p, v, __ATOMIC_RELAXED, __HIP_MEMORY_SCOPE_AGENT);
}

// 16 x 16B fragment loads from IC in ONE asm block (cannot be re-serialized).
// Frag-major layout: per-kb stride = 1024 B; 4 bases cover kb {0-3,4-7,8-11,
// 12-15} with 13-bit offsets 0/1024/2048/3072. Each instruction's 64 lanes
// read one contiguous 1 KB run.
__device__ __forceinline__ void ld_frags16(const short* p0, const short* p1,
                                           const short* p2, const short* p3,
                                           short8 f[16]) {
  short8 f0,f1,f2,f3,f4,f5,f6,f7,f8,f9,f10,f11,f12,f13,f14,f15;
  asm volatile(
    "global_load_dwordx4 %0,  %16, off sc0 sc1\n\t"
    "global_load_dwordx4 %1,  %16, off offset:1024 sc0 sc1\n\t"
    "global_load_dwordx4 %2,  %16, off offset:2048 sc0 sc1\n\t"
    "global_load_dwordx4 %3,  %16, off offset:3072 sc0 sc1\n\t"
    "global_load_dwordx4 %4,  %17, off sc0 sc1\n\t"
    "global_load_dwordx4 %5,  %17, off offset:1024 sc0 sc1\n\t"
    "global_load_dwordx4 %6,  %17, off offset:2048 sc0 sc1\n\t"
    "global_load_dwordx4 %7,  %17, off offset:3072 sc0 sc1\n\t"
    "global_load_dwordx4 %8,  %18, off sc0 sc1\n\t"
    "global_load_dwordx4 %9,  %18, off offset:1024 sc0 sc1\n\t"
    "global_load_dwordx4 %10, %18, off offset:2048 sc0 sc1\n\t"
    "global_load_dwordx4 %11, %18, off offset:3072 sc0 sc1\n\t"
    "global_load_dwordx4 %12, %19, off sc0 sc1\n\t"
    "global_load_dwordx4 %13, %19, off offset:1024 sc0 sc1\n\t"
    "global_load_dwordx4 %14, %19, off offset:2048 sc0 sc1\n\t"
    "global_load_dwordx4 %15, %19, off offset:3072 sc0 sc1\n\t"
    "s_waitcnt vmcnt(0)"
    : "=&v"(f0), "=&v"(f1), "=&v"(f2), "=&v"(f3),
      "=&v"(f4), "=&v"(f5), "=&v"(f6), "=&v"(f7),
      "=&v"(f8), "=&v"(f9), "=&v"(f10), "=&v"(f11),
      "=&v"(f12), "=&v"(f13), "=&v"(f14), "=&v"(f15)
    : "v"(p0), "v"(p1), "v"(p2), "v"(p3)
    : "memory");
  f[0]=f0; f[1]=f1; f[2]=f2; f[3]=f3; f[4]=f4; f[5]=f5; f[6]=f6; f[7]=f7;
  f[8]=f8; f[9]=f9; f[10]=f10; f[11]=f11; f[12]=f12; f[13]=f13; f[14]=f14; f[15]=f15;
}

// arrive: all block stores acked at IC, then set this block's flag = phase
__device__ __forceinline__ void bar_arrive(int* flags, int c, int phase) {
  asm volatile("s_waitcnt vmcnt(0)" ::: "memory");   // sc1 stores acked at IC
  __syncthreads();                                   // whole block done
  if (threadIdx.x == 0)
    __hip_atomic_store(&flags[c], phase, __ATOMIC_RELAXED, __HIP_MEMORY_SCOPE_AGENT);
}
// wait: wave 0 gathers all 32 flags (1 load), done when min >= phase
__device__ __forceinline__ void bar_wait(int* flags, int phase) {
  if (threadIdx.x < 64) {
    int* fp = &flags[threadIdx.x & 31];
    int guard = 0;
    for (;;) {
      int f = __hip_atomic_load(fp, __ATOMIC_RELAXED, __HIP_MEMORY_SCOPE_AGENT);
      if (__all(f >= phase)) break;
      if (++guard > (1 << 15)) break;  // safety valve: degrade, never hang
    }
  }
  __syncthreads();
}

// ---------------------------------------------------------------------------
// prep: pack U mats into B-fragment order bf16; transpose W mats to [n][k] bf16
// Upk[mat][c][kb][lane][j] = U[kb*32 + (lane>>4)*8 + j][c*16 + (lane&15)]
// ---------------------------------------------------------------------------
__global__ __launch_bounds__(256) void prep_kernel(
    const float* __restrict__ U0, const float* __restrict__ U1, const float* __restrict__ U2,
    const float* __restrict__ W0, const float* __restrict__ W1, const float* __restrict__ W2,
    short* __restrict__ Upk, short* __restrict__ Wt)
{
  int e = blockIdx.x * 256 + threadIdx.x;
  if (e < 786432) {
    int mat = e >> 18;
    int rem = e & 262143;
    int c   = rem >> 13;
    int r2  = rem & 8191;
    int kb  = r2 >> 9;
    int r3  = r2 & 511;
    int l = r3 >> 3, j = r3 & 7;
    int k = kb * 32 + ((l >> 4) << 3) + j;
    int d = c * 16 + (l & 15);
    const float* U = (mat == 0) ? U0 : (mat == 1 ? U1 : U2);
    Upk[e] = f2b(U[k * 512 + d]);
  } else if (e < 1572864) {
    int e2 = e - 786432;
    int mat = e2 >> 18;
    int rem = e2 & 262143;
    int n = rem >> 9, k = rem & 511;
    const float* W = (mat == 0) ? W0 : (mat == 1 ? W1 : W2);
    Wt[e2] = f2b(W[k * 512 + n]);
  }
}

__global__ __launch_bounds__(256) void init_kernel(short* h_bf, float* h_f32) {
  int e = blockIdx.x * 256 + threadIdx.x;
  if (e < 32768) { h_bf[e] = 0; h_f32[e] = 0.0f; }
}

// ---------------------------------------------------------------------------
// GEMM (per segment): out[mat][m][n] = bf16( X-row(base+m) . W[mat][:,n] + b )
// global row g = t*64 + b maps to X[b][t][:]. 128x128 tile, BK=32, 4 waves.
// Also resets the 32 barrier flags (block (0,0,0), tid<32).
// ---------------------------------------------------------------------------
__global__ __launch_bounds__(256) void gemm_xw(
    const float* __restrict__ X, const short* __restrict__ Wt,
    const float* __restrict__ bias0, const float* __restrict__ bias1,
    const float* __restrict__ bias2, short* __restrict__ out,
    int base_row, int cnt_rows, int* flags)
{
  if (blockIdx.x == 0 && blockIdx.y == 0 && blockIdx.z == 0 && threadIdx.x < 32)
    flags[threadIdx.x] = 0;
  __shared__ __align__(16) short Al[128][48];  // +16 pad: break 8-way conflicts
  __shared__ __align__(16) short Bl[128][48];
  const int bm = blockIdx.x, bn = blockIdx.y, mat = blockIdx.z;
  const short* Wm = Wt + (size_t)mat * (512 * 512);
  const float* bias = (mat == 0) ? bias0 : (mat == 1 ? bias1 : bias2);
  short* om = out + (size_t)mat * ((size_t)cnt_rows * 512);
  const int tid = threadIdx.x, lane = tid & 63, wid = tid >> 6;
  const int wm = wid >> 1, wn = wid & 1;
  const int m0 = bm * 128, n0g = bn * 128;
  f32x4 acc[4][4];
  #pragma unroll
  for (int i = 0; i < 4; ++i)
    #pragma unroll
    for (int j = 0; j < 4; ++j) acc[i][j] = (f32x4){0.f, 0.f, 0.f, 0.f};

  for (int k0 = 0; k0 < 512; k0 += 32) {
    #pragma unroll
    for (int i = 0; i < 4; ++i) {
      int q = tid + 256 * i;          // 0..1023 float4-slots (128 rows x 8)
      int r = q >> 3, seg = q & 7;
      int ml = m0 + r;
      short4v h4 = {0, 0, 0, 0};
      if (ml < cnt_rows) {
        int gl = base_row + ml;
        int t = gl >> 6, bb = gl & 63;
        floatx4 v = *(const floatx4*)(X + ((size_t)bb * 512 + t) * 512 + k0 + seg * 4);
        h4 = (short4v){ f2b(v[0]), f2b(v[1]), f2b(v[2]), f2b(v[3]) };
      }
      *(short4v*)&Al[r][seg * 4] = h4;
    }
    #pragma unroll
    for (int i = 0; i < 2; ++i) {
      int q = tid + 256 * i;          // 0..511 short8-slots (128 rows x 4)
      int r = q >> 2, seg = q & 3;
      *(short8*)&Bl[r][seg * 8] = *(const short8*)(Wm + (size_t)(n0g + r) * 512 + k0 + seg * 8);
    }
    __syncthreads();
    const int ko = (lane >> 4) * 8;
    short8 af[4], bf4[4];
    #pragma unroll
    for (int mt = 0; mt < 4; ++mt)
      af[mt] = *(const short8*)&Al[wm * 64 + mt * 16 + (lane & 15)][ko];
    #pragma unroll
    for (int nt = 0; nt < 4; ++nt)
      bf4[nt] = *(const short8*)&Bl[wn * 64 + nt * 16 + (lane & 15)][ko];
    #pragma unroll
    for (int mt = 0; mt < 4; ++mt)
      #pragma unroll
      for (int nt = 0; nt < 4; ++nt)
        acc[mt][nt] = __builtin_amdgcn_mfma_f32_16x16x32_bf16(af[mt], bf4[nt], acc[mt][nt], 0, 0, 0);
    __syncthreads();
  }
  // epilogue: + bias, store bf16.  C/D layout: col=lane&15, row=(lane>>4)*4+rr
  const int rq = lane >> 4, cq = lane & 15;
  #pragma unroll
  for (int mt = 0; mt < 4; ++mt) {
    #pragma unroll
    for (int nt = 0; nt < 4; ++nt) {
      int n = n0g + wn * 64 + nt * 16 + cq;
      float bv = bias[n];
      #pragma unroll
      for (int rr = 0; rr < 4; ++rr) {
        int m = m0 + wm * 64 + mt * 16 + rq * 4 + rr;
        if (m < cnt_rows) om[(size_t)m * 512 + n] = f2b(acc[mt][nt][rr] + bv);
      }
    }
  }
}

// ---------------------------------------------------------------------------
// scan segment: 32 blocks x 256 threads (4 waves). Block c owns cols
// [c*16, c*16+16). Wave w owns batch rows [w*16, w*16+16). U slices in LDS.
// h_bf/g_bf frag-major: idx(row,col) = (row>>4)*8192 + (col>>5)*512
//                     + ((col>>3)&3)*128 + (row&15)*8 + (col&7)
// ---------------------------------------------------------------------------
__global__ __launch_bounds__(256, 1) void scan_kernel(
    short* h_bf, short* g_bf, float* h_f32,
    const short* __restrict__ Upk,
    const short* __restrict__ xx,
    int* flags,
    const float* __restrict__ bu_in, const float* __restrict__ bu_out,
    float* __restrict__ out,
    int s0, int nsteps, int nt)
{
  __shared__ __align__(16) short Ub[3][16][64][8];   // 48 KB, B-frag-packed
  const int tid = threadIdx.x, lane = tid & 63, wid = tid >> 6;
  const int c = blockIdx.x;
  const int n0 = c * 16;
  {
    const size_t cs = (size_t)c * 8192;
    short8* dst = (short8*)Ub;
    for (int i = tid; i < 3072; i += 256) {          // 48 KB in 12 iters
      int mat = i >> 10;
      int rem = i & 1023;
      dst[i] = *(const short8*)(Upk + (size_t)mat * 262144 + cs + (size_t)rem * 8);
    }
  }
  const int colg = n0 + (lane & 15);
  const float binr  = bu_in[colg];
  const float boutr = bu_out[colg];
  const int m0 = wid * 16;
  const size_t XSZ = (size_t)nt * 64 * 512;
  // frag-load bases (frag-major layout): lane reads kb-run at
  // w*8192 + kb*512 + (lane>>4)*128 + (lane&15)*8
  const int fofs = wid * 8192 + ((lane >> 4) << 7) + ((lane & 15) << 3);
  const short* hp0 = h_bf + fofs;            // kb 0-3
  const short* hp1 = hp0 + 2048;             // kb 4-7
  const short* hp2 = hp0 + 4096;             // kb 8-11
  const short* hp3 = hp0 + 6144;             // kb 12-15
  const short* gp0 = g_bf + fofs;
  const short* gp1 = gp0 + 2048;
  const short* gp2 = gp0 + 4096;
  const short* gp3 = gp0 + 6144;
  // store base (row gr = m0+(lane>>4)*4+r, col = colg):
  // wid*8192 + (c>>1)*512 + ((c&1)*2 + ((lane&15)>>3))*128 + (gr&15)*8 + (lane&7)
  const int stofs = wid * 8192 + ((c >> 1) << 9)
                  + (((c & 1) * 2 + ((lane & 15) >> 3)) << 7) + (lane & 7);
  short* hst = h_bf + stofs;
  short* gst = g_bf + stofs;
  // own h tile fp32, C-frag layout: hown[r] = h[m0+(lane>>4)*4+r][colg]
  float hown[4];
  #pragma unroll
  for (int r = 0; r < 4; ++r)
    hown[r] = h_f32[(size_t)(m0 + (lane >> 4) * 4 + r) * 512 + colg];
  __syncthreads();

  for (int s = 0; s < nsteps; ++s) {
    // hoisted xx loads for stage 1 (read-only, cached) — overlap barrier wait
    float a1[4], a0[4], p1[4], p0[4];
    #pragma unroll
    for (int r = 0; r < 4; ++r) {
      int gr = m0 + (lane >> 4) * 4 + r;
      size_t i1 = ((size_t)(s + 1) * 64 + gr) * 512 + colg;
      size_t i0 = ((size_t)s * 64 + gr) * 512 + colg;
      a1[r] = b2f(xx[i1]);       a0[r] = b2f(xx[i0]);
      p1[r] = b2f(xx[XSZ + i1]); p0[r] = b2f(xx[XSZ + i0]);
    }
    if (s > 0) bar_wait(flags, 2 * s);            // prev step's h at IC

    // ---- stage 1: h@U, h@U_in. 16 frag loads in ONE asm block, then mfma ----
    short8 afr[16];
    ld_frags16(hp0, hp1, hp2, hp3, afr);
    f32x4 accu  = {0.f, 0.f, 0.f, 0.f};
    f32x4 accin = {0.f, 0.f, 0.f, 0.f};
    #pragma unroll
    for (int kb = 0; kb < 16; ++kb) {
      short8 b0 = *((const short8*)Ub + ((0 * 16 + kb) * 64 + lane));
      short8 b1 = *((const short8*)Ub + ((1 * 16 + kb) * 64 + lane));
      accu  = __builtin_amdgcn_mfma_f32_16x16x32_bf16(afr[kb], b0, accu, 0, 0, 0);
      accin = __builtin_amdgcn_mfma_f32_16x16x32_bf16(afr[kb], b1, accin, 0, 0, 0);
    }
    float zr[4];
    #pragma unroll
    for (int r = 0; r < 4; ++r) {
      zr[r] = hsig(a1[r] + accu[r] + a0[r]);
      float zin = hsig(p1[r] + accin[r] + p0[r] + binr);
      st2_cp(gst + (((lane >> 4) * 4 + r) << 3), f2b(zin * hown[r]));
    }
    bar_arrive(flags, c, 2 * s + 1);               // g published

    // hoisted xx loads for stage 2 — overlap barrier wait
    float q1[4], q0[4];
    #pragma unroll
    for (int r = 0; r < 4; ++r) {
      int gr = m0 + (lane >> 4) * 4 + r;
      size_t i1 = ((size_t)(s + 1) * 64 + gr) * 512 + colg;
      size_t i0 = ((size_t)s * 64 + gr) * 512 + colg;
      q1[r] = b2f(xx[2 * XSZ + i1]); q0[r] = b2f(xx[2 * XSZ + i0]);
    }
    bar_wait(flags, 2 * s + 1);                    // everyone's g at IC

    // ---- stage 2: (z_in*h)@U_out. Same one-asm-block load structure ----
    short8 gfr[16];
    ld_frags16(gp0, gp1, gp2, gp3, gfr);
    f32x4 acco = {0.f, 0.f, 0.f, 0.f};
    #pragma unroll
    for (int kb = 0; kb < 16; ++kb) {
      short8 b2 = *((const short8*)Ub + ((2 * 16 + kb) * 64 + lane));
      acco = __builtin_amdgcn_mfma_f32_16x16x32_bf16(gfr[kb], b2, acco, 0, 0, 0);
    }
    #pragma unroll
    for (int r = 0; r < 4; ++r) {
      int gr = m0 + (lane >> 4) * 4 + r;
      float pre = q1[r] + acco[r] + q0[r] + boutr;
      float zo = softplus_f(pre);
      float hn = (1.0f - zr[r]) * hown[r] + zr[r] * zo;
      hown[r] = hn;
      st2_cp(hst + (((lane >> 4) * 4 + r) << 3), f2b(hn));
      if (s0 + s == NSTEP - 1) out[(size_t)gr * 512 + colg] = hn;
    }
    if (s < nsteps - 1) bar_arrive(flags, c, 2 * s + 2);  // h published
  }
  // persist fp32 h for the next segment (launch boundary = global sync)
  #pragma unroll
  for (int r = 0; r < 4; ++r)
    h_f32[(size_t)(m0 + (lane >> 4) * 4 + r) * 512 + colg] = hown[r];
}

extern "C" void kernel_launch(void* const* d_in, const int* in_sizes, int n_in,
                              void* d_out, int out_size, void* d_ws, size_t ws_size,
                              hipStream_t stream)
{
  const float* X      = (const float*)d_in[0];
  const float* W      = (const float*)d_in[1];
  const float* b      = (const float*)d_in[2];
  const float* W_in   = (const float*)d_in[3];
  const float* b_in   = (const float*)d_in[4];
  const float* W_out  = (const float*)d_in[5];
  const float* b_out  = (const float*)d_in[6];
  const float* U      = (const float*)d_in[7];
  const float* U_in   = (const float*)d_in[8];
  const float* U_out  = (const float*)d_in[9];
  const float* bu_in  = (const float*)d_in[10];
  const float* bu_out = (const float*)d_in[11];
  float* out = (float*)d_out;
  char* ws = (char*)d_ws;
  int*   flags = (int*)(ws + OFF_FLG);
  short* h_bf = (short*)(ws + OFF_HBF);
  short* g_bf = (short*)(ws + OFF_GBF);
  float* h_f32= (float*)(ws + OFF_HF32);
  short* Upk  = (short*)(ws + OFF_UPK);
  short* Wt   = (short*)(ws + OFF_WT);
  short* xx   = (short*)(ws + OFF_XX);

  // size the scan segment to the available workspace
  size_t avail = (ws_size > (size_t)OFF_XX) ? ws_size - (size_t)OFF_XX : 0;
  int max_t = (int)(avail / PER_T_BYTES);          // storable time rows
  if (max_t > 512) max_t = 512;
  int SEG = max_t - 1;                             // steps per segment
  if (SEG < 1) SEG = 1;                            // (ws too small: best effort)

  prep_kernel<<<6144, 256, 0, stream>>>(U, U_in, U_out, W, W_in, W_out, Upk, Wt);
  init_kernel<<<128, 256, 0, stream>>>(h_bf, h_f32);

  int s0 = 0;
  while (s0 < NSTEP) {
    int nsteps = NSTEP - s0; if (nsteps > SEG) nsteps = SEG;
    int nt = nsteps + 1;
    int rows = nt * 64;
    int gx = (rows + 127) / 128;
    gemm_xw<<<dim3(gx, 4, 3), 256, 0, stream>>>(X, Wt, b, b_in, b_out, xx,
                                                s0 * 64, rows, flags);
    scan_kernel<<<NBLK, 256, 0, stream>>>(h_bf, g_bf, h_f32, Upk, xx, flags,
                                          bu_in, bu_out, out, s0, nsteps, nt);
    s0 += nsteps;
  }
}